// Round 5
// baseline (6611.779 us; speedup 1.0000x reference)
//
#include <hip/hip_runtime.h>
#include <hip/hip_bf16.h>
#include <math.h>

#define BB 8
#define NN 8192
#define SS 2048
#define NSAMP 32

typedef unsigned long long u64;

// K0: transpose xyz (B,3,N) f32 -> X (B,N,3) f32
__global__ void k_transpose(const float* __restrict__ xyz, float* __restrict__ X) {
    int e = blockIdx.x * 256 + threadIdx.x;
    if (e >= BB * 3 * NN) return;
    int n = e % NN;
    int bc = e / NN;
    int c = bc % 3;
    int b = bc / 3;
    X[((size_t)(b * NN + n)) * 3 + c] = xyz[e];
}

// K1: farthest point sampling, one block per batch.
// ARITHMETIC FROZEN (bit-exact vs reference, r18 PASS): direct distance,
// ascending, separately rounded (NO FMA); dists=fminf; argmax=first-max
// (smallest global index on ties; (v,n) lexicographic max is associative &
// commutative so combine order across chains/waves is free).
// History: r19 coords-in-VGPR: compiler remat'd -> 3.0ms. r20/r21 allocator
// hints: failed (132 VGPR, partial remat; payload shuffles regressed ->
// 4.3ms). r22 LDS-staged points @256thr: bank-conflict-free but LDS-LATENCY
// bound at 1 wave/SIMD -- per-i {3x ds_read -> lgkmcnt -> compute} chain,
// ~146 cyc x 32 = 4532 cyc/step measured, nothing to overlap stalls with.
// r23: SAME LDS structure, 1024 threads = 16 waves = 4 waves/SIMD -> TLP
// hides ds_read latency (r19's "1024 slower" was the remat'd global-load
// version; issue work is thread-count-invariant now). 8 points/thread;
// loads hoisted into register batches (static indexing) so all 24 ds_reads
// issue under one waitcnt; 16-entry cross-wave scan (independent loads,
// ~130 cyc). Budget ~1300 cyc/step -> ~1.1-1.5 ms.
// r24: identical resubmit — r23's bench was an infra failure (container
// acquisition died twice; no dispatch-level evidence of a kernel fault).
__global__ __launch_bounds__(1024) void k_fps(const float* __restrict__ X,
                                              float* __restrict__ NXYZ) {
    __shared__ float lx[NN], ly[NN], lz[NN];  // 96 KB point cache
    __shared__ float wv_[2][16];
    __shared__ int wn_[2][16];
    int b = blockIdx.x;
    int tid = threadIdx.x;
    const float* xb = X + (size_t)b * NN * 3;
    // one-time stage (pure bit-copy; ~96 KB from L2)
    for (int e = tid; e < NN; e += 1024) {
        lx[e] = xb[(size_t)e * 3 + 0];
        ly[e] = xb[(size_t)e * 3 + 1];
        lz[e] = xb[(size_t)e * 3 + 2];
    }
    float dist[8];
#pragma unroll
    for (int i = 0; i < 8; ++i) dist[i] = 1e10f;
    float c0 = xb[0], c1 = xb[1], c2 = xb[2];
    int lane = tid & 63, wv = tid >> 6;  // wv in 0..15
    __syncthreads();
    for (int t = 0; t < SS; ++t) {
        if (tid == 0) {
            float* o = NXYZ + ((size_t)b * SS + t) * 3;
            o[0] = c0; o[1] = c1; o[2] = c2;
        }
        // batch all 24 LDS reads first (independent, one waitcnt), then compute
        float pxl[8], pyl[8], pzl[8];
#pragma unroll
        for (int i = 0; i < 8; ++i) {
            int n = tid + (i << 10);
            pxl[i] = lx[n];
            pyl[i] = ly[n];
            pzl[i] = lz[n];
        }
        // 2 independent scan chains over ascending i-blocks; strict > keeps
        // the first (smallest-n) max within a chain; chains combined in
        // ascending-n order with strict > => identical semantics.
        float bv0 = -1.0f, bv1 = -1.0f;
        int bn0 = 0, bn1 = 0;
#pragma unroll
        for (int i = 0; i < 8; ++i) {
            float dx = __fsub_rn(pxl[i], c0);
            float dy = __fsub_rn(pyl[i], c1);
            float dz = __fsub_rn(pzl[i], c2);
            float dd = __fadd_rn(__fadd_rn(__fmul_rn(dx, dx), __fmul_rn(dy, dy)),
                                 __fmul_rn(dz, dz));
            float nd = fminf(dist[i], dd);
            dist[i] = nd;
            int n = tid + (i << 10);
            if (i < 4) {
                if (nd > bv0) { bv0 = nd; bn0 = n; }
            } else {
                if (nd > bv1) { bv1 = nd; bn1 = n; }
            }
        }
        float bestv = bv0; int bestn = bn0;
        if (bv1 > bestv) { bestv = bv1; bestn = bn1; }
        // wave-level reduction: max value, ties -> smallest index
#pragma unroll
        for (int off = 32; off > 0; off >>= 1) {
            float ov = __shfl_down(bestv, (unsigned)off, 64);
            int on = __shfl_down(bestn, (unsigned)off, 64);
            if (ov > bestv || (ov == bestv && on < bestn)) { bestv = ov; bestn = on; }
        }
        int pbuf = t & 1;
        if (lane == 0) { wv_[pbuf][wv] = bestv; wn_[pbuf][wv] = bestn; }
        __syncthreads();
        // 16-entry cross-wave scan (all loads independent; ~4 VALU/entry)
        float kv = wv_[pbuf][0]; int kn = wn_[pbuf][0];
#pragma unroll
        for (int i = 1; i < 16; ++i) {
            float ov = wv_[pbuf][i]; int on = wn_[pbuf][i];
            if (ov > kv || (ov == kv && on < kn)) { kv = ov; kn = on; }
        }
        // broadcast LDS read of the winner's coords (bit-identical copy)
        c0 = lx[kn]; c1 = ly[kn]; c2 = lz[kn];
        // no trailing barrier: next step writes the other wv_/wn_ slot; the
        // write-after-next is separated from this read by the next barrier.
    }
}

// K2: ball query. One wave per center. ARITHMETIC FROZEN (r18 PASS):
//   dot = fma(c2,x2, fma(c1,x1, fl(c0*x0)))   (BLAS k=3 asc-FMA)
//   t   = fl(-2*dot + B)   B = (x0^2+x1^2)+x2^2  (asc, no FMA)
//   sqr = fl(t + A)        A = (c0^2+c1^2)+c2^2  (asc, no FMA)
//   exclude sqr > 0.04f
__global__ __launch_bounds__(256) void k_ballq(const float* __restrict__ X,
                                               const float* __restrict__ NXYZ,
                                               int* __restrict__ GI) {
    int wv = threadIdx.x >> 6, lane = threadIdx.x & 63;
    int gs = blockIdx.x * 4 + wv;           // 0..16383
    int b = gs >> 11;
    const float* xb = X + (size_t)b * NN * 3;
    float c0 = NXYZ[(size_t)gs * 3 + 0];
    float c1 = NXYZ[(size_t)gs * 3 + 1];
    float c2 = NXYZ[(size_t)gs * 3 + 2];
    float A = __fadd_rn(__fadd_rn(__fmul_rn(c0, c0), __fmul_rn(c1, c1)),
                        __fmul_rn(c2, c2));
    const float R2 = 0.04f;
    int cnt = 0, first = 0;
    int* gout = GI + ((size_t)gs << 5);
    for (int r = 0; r < 128 && cnt < 32; ++r) {
        int n = (r << 6) + lane;
        float x0 = xb[(size_t)n * 3 + 0];
        float x1 = xb[(size_t)n * 3 + 1];
        float x2 = xb[(size_t)n * 3 + 2];
        float Bx = __fadd_rn(__fadd_rn(__fmul_rn(x0, x0), __fmul_rn(x1, x1)),
                             __fmul_rn(x2, x2));
        float dot = fmaf(c2, x2, fmaf(c1, x1, __fmul_rn(c0, x0)));  // BLAS asc-FMA
        float t = __fadd_rn(__fmul_rn(-2.0f, dot), Bx);             // += B first
        float sqr = __fadd_rn(t, A);                                // += A second
        bool pred = !(sqr > R2);
        u64 mask = __ballot(pred);
        int rank = cnt + __popcll(mask & ((1ull << lane) - 1ull));
        if (pred && rank < 32) gout[rank] = n;
        if (cnt == 0 && mask) first = (r << 6) + (__ffsll((long long)mask) - 1);
        cnt += __popcll(mask);
    }
    if (cnt < 32 && lane >= cnt && lane < 32) gout[lane] = first;
}

// K3: build group features in LDS + attention block 1 + maxpool. One block per
// (b,s) group: 32 tokens x 64 dims.
__global__ __launch_bounds__(256) void k_attn1(
    const float* __restrict__ X, const float* __restrict__ NXYZ,
    const int* __restrict__ GI, const float* __restrict__ P,
    const float* __restrict__ wq, const float* __restrict__ wk,
    const float* __restrict__ wv, const float* __restrict__ wo,
    const float* __restrict__ wp, const float* __restrict__ bp,
    float* __restrict__ FMID) {
    __shared__ float feat[32][65], qS[32][65], kS[32][65], vS[32][65];
    __shared__ float sc[32][33];
    __shared__ float pos[32][3];
    __shared__ int giS[32];
    __shared__ float ctr[3];
    int gs = blockIdx.x;
    int b = gs >> 11;
    int tid = threadIdx.x;
    if (tid < 32) giS[tid] = GI[((size_t)gs << 5) + tid];
    if (tid < 3) ctr[tid] = NXYZ[(size_t)gs * 3 + tid];
    __syncthreads();
    const float* xb = X + (size_t)b * NN * 3;
    const float* pb = P + (size_t)b * 61 * NN;
    int d = tid & 63, g4 = tid >> 6;
    for (int jj = 0; jj < 8; ++jj) {
        int j = g4 * 8 + jj;
        int idx = giS[j];
        float val;
        if (d < 3) {
            float xv = xb[(size_t)idx * 3 + d];
            pos[j][d] = xv;
            val = __fsub_rn(xv, ctr[d]);
        } else {
            val = pb[(size_t)(d - 3) * NN + idx];
        }
        feat[j][d] = val;
    }
    __syncthreads();
    float aq[8], ak[8], av[8];
#pragma unroll
    for (int i = 0; i < 8; ++i) { aq[i] = 0.f; ak[i] = 0.f; av[i] = 0.f; }
    for (int kk = 0; kk < 64; ++kk) {
        float wqv = wq[kk * 64 + d];
        float wkv = wk[kk * 64 + d];
        float wvv = wv[kk * 64 + d];
#pragma unroll
        for (int i = 0; i < 8; ++i) {
            float f = feat[g4 + 4 * i][kk];
            aq[i] = fmaf(f, wqv, aq[i]);
            ak[i] = fmaf(f, wkv, ak[i]);
            av[i] = fmaf(f, wvv, av[i]);
        }
    }
    {
        float wp0 = wp[d], wp1 = wp[64 + d], wp2 = wp[128 + d];
        float bpd = bp[d];
#pragma unroll
        for (int i = 0; i < 8; ++i) {
            int j = g4 + 4 * i;
            float pterm = fmaf(pos[j][2], wp2, fmaf(pos[j][1], wp1, pos[j][0] * wp0)) + bpd;
            av[i] += pterm;
            qS[j][d] = aq[i]; kS[j][d] = ak[i]; vS[j][d] = av[i];
        }
    }
    __syncthreads();
    for (int e = tid; e < 1024; e += 256) {
        int r = e >> 5, ci = e & 31;
        float acc = 0.f;
        for (int kk = 0; kk < 64; ++kk) acc = fmaf(qS[r][kk], kS[ci][kk], acc);
        sc[r][ci] = acc * 0.125f;
    }
    __syncthreads();
    if (tid < 32) {
        float m = -INFINITY;
        for (int i2 = 0; i2 < 32; ++i2) m = fmaxf(m, sc[tid][i2]);
        float sum = 0.f;
        for (int i2 = 0; i2 < 32; ++i2) {
            float e2 = expf(sc[tid][i2] - m);
            sc[tid][i2] = e2; sum += e2;
        }
        float inv = 1.0f / sum;
        for (int i2 = 0; i2 < 32; ++i2) sc[tid][i2] *= inv;
    }
    __syncthreads();
    // a @ v -> reuse qS as attention output
    for (int e = tid; e < 2048; e += 256) {
        int j = e >> 6, dd2 = e & 63;
        float acc = 0.f;
        for (int s2 = 0; s2 < 32; ++s2) acc = fmaf(sc[j][s2], vS[s2][dd2], acc);
        qS[j][dd2] = acc;
    }
    __syncthreads();
    float o[8];
#pragma unroll
    for (int i = 0; i < 8; ++i) o[i] = feat[g4 + 4 * i][d];
    for (int kk = 0; kk < 64; ++kk) {
        float wov = wo[kk * 64 + d];
#pragma unroll
        for (int i = 0; i < 8; ++i) o[i] = fmaf(qS[g4 + 4 * i][kk], wov, o[i]);
    }
    float pm = o[0];
#pragma unroll
    for (int i = 1; i < 8; ++i) pm = fmaxf(pm, o[i]);
    __syncthreads();
    feat[g4][d] = pm;
    __syncthreads();
    if (tid < 64) {
        float mm = fmaxf(fmaxf(feat[0][tid], feat[1][tid]),
                         fmaxf(feat[2][tid], feat[3][tid]));
        FMID[((size_t)gs << 6) + tid] = mm;
    }
}

// K4: q/k/v projections for attention block 2 (rows = B*2048)
__global__ __launch_bounds__(256) void k_qkv2(
    const float* __restrict__ FMID, const float* __restrict__ NXYZ,
    const float* __restrict__ wq, const float* __restrict__ wk,
    const float* __restrict__ wv, const float* __restrict__ wp,
    const float* __restrict__ bpv,
    float* __restrict__ Q2, float* __restrict__ K2, float* __restrict__ V2) {
    __shared__ float f[4][65];
    int tid = threadIdx.x;
    int lr = tid >> 6, d = tid & 63;
    size_t row = (size_t)blockIdx.x * 4 + lr;
    f[lr][d] = FMID[row * 64 + d];
    __syncthreads();
    float aq = 0.f, ak = 0.f, av = 0.f;
    for (int kk = 0; kk < 64; ++kk) {
        float fv = f[lr][kk];
        aq = fmaf(fv, wq[kk * 64 + d], aq);
        ak = fmaf(fv, wk[kk * 64 + d], ak);
        av = fmaf(fv, wv[kk * 64 + d], av);
    }
    float p0 = NXYZ[row * 3], p1 = NXYZ[row * 3 + 1], p2 = NXYZ[row * 3 + 2];
    av += fmaf(p2, wp[128 + d], fmaf(p1, wp[64 + d], p0 * wp[d])) + bpv[d];
    Q2[row * 64 + d] = aq; K2[row * 64 + d] = ak; V2[row * 64 + d] = av;
}

// K5: attention block 2, flash-style online softmax. 16 Q-rows per block
// (4 waves x 4 rows), K/V staged in padded LDS tiles of 64 rows.
__global__ __launch_bounds__(256) void k_attn2(
    const float* __restrict__ Q2, const float* __restrict__ K2,
    const float* __restrict__ V2, const float* __restrict__ FMID,
    const float* __restrict__ wo, float* __restrict__ out1) {
    __shared__ float kT[64][65], vT[64][65], qSh[16][65];
    int tid = threadIdx.x;
    int wv = tid >> 6, lane = tid & 63;
    int b = blockIdx.x >> 7, rb = blockIdx.x & 127;
    size_t rbase = (size_t)b * SS + rb * 16;
    for (int e = tid; e < 16 * 64; e += 256) {
        int r = e >> 6, dd = e & 63;
        qSh[r][dd] = Q2[(rbase + r) * 64 + dd];
    }
    float acc[4] = {0.f, 0.f, 0.f, 0.f};
    float mr[4] = {-INFINITY, -INFINITY, -INFINITY, -INFINITY};
    float lr[4] = {0.f, 0.f, 0.f, 0.f};
    for (int tt = 0; tt < 32; ++tt) {
        __syncthreads();
        for (int e = tid; e < 4096; e += 256) {
            int r = e >> 6, dd = e & 63;
            size_t src = ((size_t)b * SS + tt * 64 + r) * 64 + dd;
            kT[r][dd] = K2[src];
            vT[r][dd] = V2[src];
        }
        __syncthreads();
#pragma unroll
        for (int rr = 0; rr < 4; ++rr) {
            int lrow = wv * 4 + rr;
            float sj = 0.f;
            for (int dd = 0; dd < 64; ++dd) sj = fmaf(qSh[lrow][dd], kT[lane][dd], sj);
            sj *= 0.125f;
            float tm = sj;
#pragma unroll
            for (int off = 32; off > 0; off >>= 1)
                tm = fmaxf(tm, __shfl_down(tm, (unsigned)off, 64));
            tm = __shfl(tm, 0, 64);
            float mnew = fmaxf(mr[rr], tm);
            float alpha = expf(mr[rr] - mnew);
            float pj = expf(sj - mnew);
            float ps = pj;
#pragma unroll
            for (int off = 32; off > 0; off >>= 1) ps += __shfl_down(ps, (unsigned)off, 64);
            ps = __shfl(ps, 0, 64);
            lr[rr] = lr[rr] * alpha + ps;
            float a2 = acc[rr] * alpha;
            for (int j = 0; j < 64; ++j) {
                float pb2 = __shfl(pj, j, 64);
                a2 = fmaf(pb2, vT[j][lane], a2);
            }
            acc[rr] = a2;
            mr[rr] = mnew;
        }
    }
#pragma unroll
    for (int rr = 0; rr < 4; ++rr) {
        int lrow = wv * 4 + rr;
        size_t row = rbase + lrow;
        float avl = acc[rr] / lr[rr];
        float o = FMID[row * 64 + lane];
        for (int kk = 0; kk < 64; ++kk) {
            float avk = __shfl(avl, kk, 64);
            o = fmaf(avk, wo[kk * 64 + lane], o);
        }
        out1[((size_t)b * 64 + lane) * SS + (size_t)(rb * 16 + lrow)] = o;
    }
}

// K6: new_xyz (B,S,3) f32 -> out0 (B,3,S) f32
__global__ void k_out0(const float* __restrict__ NXYZ, float* __restrict__ out0) {
    int e = blockIdx.x * 256 + threadIdx.x;
    if (e >= BB * 3 * SS) return;
    int s = e % SS;
    int bc = e / SS;
    int c = bc % 3;
    int b = bc / 3;
    out0[e] = NXYZ[((size_t)b * SS + s) * 3 + c];
}

extern "C" void kernel_launch(void* const* d_in, const int* in_sizes, int n_in,
                              void* d_out, int out_size, void* d_ws, size_t ws_size,
                              hipStream_t stream) {
    const float* xyz = (const float*)d_in[0];
    const float* pts = (const float*)d_in[1];
    const float* w1q = (const float*)d_in[2];
    const float* w1k = (const float*)d_in[3];
    const float* w1v = (const float*)d_in[4];
    const float* w1o = (const float*)d_in[5];
    const float* w1p = (const float*)d_in[6];
    const float* b1p = (const float*)d_in[7];
    const float* w2q = (const float*)d_in[8];
    const float* w2k = (const float*)d_in[9];
    const float* w2v = (const float*)d_in[10];
    const float* w2o = (const float*)d_in[11];
    const float* w2p = (const float*)d_in[12];
    const float* b2p = (const float*)d_in[13];

    float* X = (float*)d_ws;                               // B*N*3
    float* NXYZ = X + (size_t)BB * NN * 3;                 // B*S*3
    int* GI = (int*)(NXYZ + (size_t)BB * SS * 3);          // B*S*32
    float* FMID = (float*)(GI + (size_t)BB * SS * 32);     // B*S*64
    float* Q2 = FMID + (size_t)BB * SS * 64;
    float* K2 = Q2 + (size_t)BB * SS * 64;
    float* V2 = K2 + (size_t)BB * SS * 64;

    float* out0 = (float*)d_out;
    float* out1 = out0 + (size_t)BB * 3 * SS;

    k_transpose<<<768, 256, 0, stream>>>(xyz, X);
    k_fps<<<BB, 1024, 0, stream>>>(X, NXYZ);
    k_ballq<<<4096, 256, 0, stream>>>(X, NXYZ, GI);
    k_attn1<<<16384, 256, 0, stream>>>(X, NXYZ, GI, pts, w1q, w1k, w1v, w1o,
                                       w1p, b1p, FMID);
    k_qkv2<<<4096, 256, 0, stream>>>(FMID, NXYZ, w2q, w2k, w2v, w2p, b2p,
                                     Q2, K2, V2);
    k_attn2<<<1024, 256, 0, stream>>>(Q2, K2, V2, FMID, w2o, out1);
    k_out0<<<192, 256, 0, stream>>>(NXYZ, out0);
}

// Round 6
// 5084.035 us; speedup vs baseline: 1.3005x; 1.3005x over previous
//
#include <hip/hip_runtime.h>
#include <hip/hip_bf16.h>
#include <math.h>

#define BB 8
#define NN 8192
#define SS 2048
#define NSAMP 32

typedef unsigned long long u64;

// K0: transpose xyz (B,3,N) f32 -> X (B,N,3) f32
__global__ void k_transpose(const float* __restrict__ xyz, float* __restrict__ X) {
    int e = blockIdx.x * 256 + threadIdx.x;
    if (e >= BB * 3 * NN) return;
    int n = e % NN;
    int bc = e / NN;
    int c = bc % 3;
    int b = bc / 3;
    X[((size_t)(b * NN + n)) * 3 + c] = xyz[e];
}

// K1: farthest point sampling, one block per batch.
// ARITHMETIC FROZEN (bit-exact vs reference, r18 PASS): direct distance,
// ascending, separately rounded (NO FMA); dists=fminf; argmax=first-max
// (smallest global index on ties; (v,n) lexicographic max is associative &
// commutative so combine order across chains/waves is free).
// History: r19 coords-in-VGPR @256thr: demand 128 floats > occupancy cap 64
// -> compiler remat'd (3.0ms). r20/r21 allocator hints: can't stop remat
// under pressure. r22 LDS @256thr: DS-latency bound (4532 cyc/step, 3.9ms).
// r23/r24 LDS @1024thr: WORSE (5770 cyc/step, 4.9ms) — point reads are
// scalar ds_read_b32: 384 wave-instr x 5.8 cyc = 2230 cyc/step of DS-PIPE
// THROUGHPUT (thread-count-invariant), plus __shfl = ds_bpermute on the
// SAME pipe (16 waves x 12 = 192 instr = 1100 cyc). TLP cannot hide a
// saturated pipe.
// r25: registers again, but DEMAND-SIZED: 512 thr, 16 pts/thread = 48 coord
// + 16 dist ~= 84 live VGPRs < 128 cap (4 w/SIMD) and < 256 at
// waves_per_eu(2,2) -> no remat incentive; per-step point pass touches no
// memory pipe. 96 KB LDS mirror kept ONLY for the winner-coord broadcast
// (~120 cyc vs 200-900 cyc dependent L2 load), staged once from the loaded
// registers. Reduce: in-thread 4-chain (ascending-n merge), 6-stage wave
// shfl (8 waves x 12 bpermutes = 560 cyc DS), 8-entry cross-wave scan.
// Budget ~1500-1900 cyc/step. TELL: VGPR must be ~90-120; <=60 => remat.
__global__ __launch_bounds__(512)
__attribute__((amdgpu_waves_per_eu(2, 2))) void k_fps(
    const float* __restrict__ X, float* __restrict__ NXYZ) {
    __shared__ float lx[NN], ly[NN], lz[NN];  // 96 KB winner-broadcast cache
    __shared__ float wv_[2][8];
    __shared__ int wn_[2][8];
    int b = blockIdx.x;
    int tid = threadIdx.x;
    const float* xb = X + (size_t)b * NN * 3;
    float px[16], py[16], pz[16], dist[16];
#pragma unroll
    for (int i = 0; i < 16; ++i) {
        int n = tid + (i << 9);
        px[i] = xb[(size_t)n * 3 + 0];
        py[i] = xb[(size_t)n * 3 + 1];
        pz[i] = xb[(size_t)n * 3 + 2];
        dist[i] = 1e10f;
        lx[n] = px[i]; ly[n] = py[i]; lz[n] = pz[i];  // stage broadcast mirror
    }
    // Opaque defs: keep the loaded values as register definitions.
#pragma unroll
    for (int i = 0; i < 16; ++i) {
        asm volatile("" : "+v"(px[i]), "+v"(py[i]), "+v"(pz[i]));
    }
    float c0 = xb[0], c1 = xb[1], c2 = xb[2];
    int lane = tid & 63, wv = tid >> 6;  // wv in 0..7
    __syncthreads();
    for (int t = 0; t < SS; ++t) {
        if (tid == 0) {
            float* o = NXYZ + ((size_t)b * SS + t) * 3;
            o[0] = c0; o[1] = c1; o[2] = c2;
        }
        // 4 independent scan chains over ascending i-blocks; strict > keeps
        // the first (smallest-n) max within a chain; chains combined in
        // ascending-n order with strict > => identical to sequential
        // first-max over i=0..15.
        float bv0 = -1.0f, bv1 = -1.0f, bv2 = -1.0f, bv3 = -1.0f;
        int bn0 = 0, bn1 = 0, bn2 = 0, bn3 = 0;
#pragma unroll
        for (int i = 0; i < 16; ++i) {
            float dx = __fsub_rn(px[i], c0);
            float dy = __fsub_rn(py[i], c1);
            float dz = __fsub_rn(pz[i], c2);
            float dd = __fadd_rn(__fadd_rn(__fmul_rn(dx, dx), __fmul_rn(dy, dy)),
                                 __fmul_rn(dz, dz));
            float nd = fminf(dist[i], dd);
            dist[i] = nd;
            int n = tid + (i << 9);
            if (i < 4) {
                if (nd > bv0) { bv0 = nd; bn0 = n; }
            } else if (i < 8) {
                if (nd > bv1) { bv1 = nd; bn1 = n; }
            } else if (i < 12) {
                if (nd > bv2) { bv2 = nd; bn2 = n; }
            } else {
                if (nd > bv3) { bv3 = nd; bn3 = n; }
            }
        }
        float bestv = bv0; int bestn = bn0;
        if (bv1 > bestv) { bestv = bv1; bestn = bn1; }
        if (bv2 > bestv) { bestv = bv2; bestn = bn2; }
        if (bv3 > bestv) { bestv = bv3; bestn = bn3; }
        // wave-level reduction: max value, ties -> smallest index
#pragma unroll
        for (int off = 32; off > 0; off >>= 1) {
            float ov = __shfl_down(bestv, (unsigned)off, 64);
            int on = __shfl_down(bestn, (unsigned)off, 64);
            if (ov > bestv || (ov == bestv && on < bestn)) { bestv = ov; bestn = on; }
        }
        int pbuf = t & 1;
        if (lane == 0) { wv_[pbuf][wv] = bestv; wn_[pbuf][wv] = bestn; }
        __syncthreads();
        // 8-entry cross-wave scan (independent loads; ~4 VALU/entry)
        float kv = wv_[pbuf][0]; int kn = wn_[pbuf][0];
#pragma unroll
        for (int i = 1; i < 8; ++i) {
            float ov = wv_[pbuf][i]; int on = wn_[pbuf][i];
            if (ov > kv || (ov == kv && on < kn)) { kv = ov; kn = on; }
        }
        // broadcast LDS read of the winner's coords (bit-identical copy)
        c0 = lx[kn]; c1 = ly[kn]; c2 = lz[kn];
        // no trailing barrier: next step writes the other wv_/wn_ slot; the
        // write-after-next is separated from this read by the next barrier.
    }
}

// K2: ball query. One wave per center. ARITHMETIC FROZEN (r18 PASS):
//   dot = fma(c2,x2, fma(c1,x1, fl(c0*x0)))   (BLAS k=3 asc-FMA)
//   t   = fl(-2*dot + B)   B = (x0^2+x1^2)+x2^2  (asc, no FMA)
//   sqr = fl(t + A)        A = (c0^2+c1^2)+c2^2  (asc, no FMA)
//   exclude sqr > 0.04f
__global__ __launch_bounds__(256) void k_ballq(const float* __restrict__ X,
                                               const float* __restrict__ NXYZ,
                                               int* __restrict__ GI) {
    int wv = threadIdx.x >> 6, lane = threadIdx.x & 63;
    int gs = blockIdx.x * 4 + wv;           // 0..16383
    int b = gs >> 11;
    const float* xb = X + (size_t)b * NN * 3;
    float c0 = NXYZ[(size_t)gs * 3 + 0];
    float c1 = NXYZ[(size_t)gs * 3 + 1];
    float c2 = NXYZ[(size_t)gs * 3 + 2];
    float A = __fadd_rn(__fadd_rn(__fmul_rn(c0, c0), __fmul_rn(c1, c1)),
                        __fmul_rn(c2, c2));
    const float R2 = 0.04f;
    int cnt = 0, first = 0;
    int* gout = GI + ((size_t)gs << 5);
    for (int r = 0; r < 128 && cnt < 32; ++r) {
        int n = (r << 6) + lane;
        float x0 = xb[(size_t)n * 3 + 0];
        float x1 = xb[(size_t)n * 3 + 1];
        float x2 = xb[(size_t)n * 3 + 2];
        float Bx = __fadd_rn(__fadd_rn(__fmul_rn(x0, x0), __fmul_rn(x1, x1)),
                             __fmul_rn(x2, x2));
        float dot = fmaf(c2, x2, fmaf(c1, x1, __fmul_rn(c0, x0)));  // BLAS asc-FMA
        float t = __fadd_rn(__fmul_rn(-2.0f, dot), Bx);             // += B first
        float sqr = __fadd_rn(t, A);                                // += A second
        bool pred = !(sqr > R2);
        u64 mask = __ballot(pred);
        int rank = cnt + __popcll(mask & ((1ull << lane) - 1ull));
        if (pred && rank < 32) gout[rank] = n;
        if (cnt == 0 && mask) first = (r << 6) + (__ffsll((long long)mask) - 1);
        cnt += __popcll(mask);
    }
    if (cnt < 32 && lane >= cnt && lane < 32) gout[lane] = first;
}

// K3: build group features in LDS + attention block 1 + maxpool. One block per
// (b,s) group: 32 tokens x 64 dims.
__global__ __launch_bounds__(256) void k_attn1(
    const float* __restrict__ X, const float* __restrict__ NXYZ,
    const int* __restrict__ GI, const float* __restrict__ P,
    const float* __restrict__ wq, const float* __restrict__ wk,
    const float* __restrict__ wv, const float* __restrict__ wo,
    const float* __restrict__ wp, const float* __restrict__ bp,
    float* __restrict__ FMID) {
    __shared__ float feat[32][65], qS[32][65], kS[32][65], vS[32][65];
    __shared__ float sc[32][33];
    __shared__ float pos[32][3];
    __shared__ int giS[32];
    __shared__ float ctr[3];
    int gs = blockIdx.x;
    int b = gs >> 11;
    int tid = threadIdx.x;
    if (tid < 32) giS[tid] = GI[((size_t)gs << 5) + tid];
    if (tid < 3) ctr[tid] = NXYZ[(size_t)gs * 3 + tid];
    __syncthreads();
    const float* xb = X + (size_t)b * NN * 3;
    const float* pb = P + (size_t)b * 61 * NN;
    int d = tid & 63, g4 = tid >> 6;
    for (int jj = 0; jj < 8; ++jj) {
        int j = g4 * 8 + jj;
        int idx = giS[j];
        float val;
        if (d < 3) {
            float xv = xb[(size_t)idx * 3 + d];
            pos[j][d] = xv;
            val = __fsub_rn(xv, ctr[d]);
        } else {
            val = pb[(size_t)(d - 3) * NN + idx];
        }
        feat[j][d] = val;
    }
    __syncthreads();
    float aq[8], ak[8], av[8];
#pragma unroll
    for (int i = 0; i < 8; ++i) { aq[i] = 0.f; ak[i] = 0.f; av[i] = 0.f; }
    for (int kk = 0; kk < 64; ++kk) {
        float wqv = wq[kk * 64 + d];
        float wkv = wk[kk * 64 + d];
        float wvv = wv[kk * 64 + d];
#pragma unroll
        for (int i = 0; i < 8; ++i) {
            float f = feat[g4 + 4 * i][kk];
            aq[i] = fmaf(f, wqv, aq[i]);
            ak[i] = fmaf(f, wkv, ak[i]);
            av[i] = fmaf(f, wvv, av[i]);
        }
    }
    {
        float wp0 = wp[d], wp1 = wp[64 + d], wp2 = wp[128 + d];
        float bpd = bp[d];
#pragma unroll
        for (int i = 0; i < 8; ++i) {
            int j = g4 + 4 * i;
            float pterm = fmaf(pos[j][2], wp2, fmaf(pos[j][1], wp1, pos[j][0] * wp0)) + bpd;
            av[i] += pterm;
            qS[j][d] = aq[i]; kS[j][d] = ak[i]; vS[j][d] = av[i];
        }
    }
    __syncthreads();
    for (int e = tid; e < 1024; e += 256) {
        int r = e >> 5, ci = e & 31;
        float acc = 0.f;
        for (int kk = 0; kk < 64; ++kk) acc = fmaf(qS[r][kk], kS[ci][kk], acc);
        sc[r][ci] = acc * 0.125f;
    }
    __syncthreads();
    if (tid < 32) {
        float m = -INFINITY;
        for (int i2 = 0; i2 < 32; ++i2) m = fmaxf(m, sc[tid][i2]);
        float sum = 0.f;
        for (int i2 = 0; i2 < 32; ++i2) {
            float e2 = expf(sc[tid][i2] - m);
            sc[tid][i2] = e2; sum += e2;
        }
        float inv = 1.0f / sum;
        for (int i2 = 0; i2 < 32; ++i2) sc[tid][i2] *= inv;
    }
    __syncthreads();
    // a @ v -> reuse qS as attention output
    for (int e = tid; e < 2048; e += 256) {
        int j = e >> 6, dd2 = e & 63;
        float acc = 0.f;
        for (int s2 = 0; s2 < 32; ++s2) acc = fmaf(sc[j][s2], vS[s2][dd2], acc);
        qS[j][dd2] = acc;
    }
    __syncthreads();
    float o[8];
#pragma unroll
    for (int i = 0; i < 8; ++i) o[i] = feat[g4 + 4 * i][d];
    for (int kk = 0; kk < 64; ++kk) {
        float wov = wo[kk * 64 + d];
#pragma unroll
        for (int i = 0; i < 8; ++i) o[i] = fmaf(qS[g4 + 4 * i][kk], wov, o[i]);
    }
    float pm = o[0];
#pragma unroll
    for (int i = 1; i < 8; ++i) pm = fmaxf(pm, o[i]);
    __syncthreads();
    feat[g4][d] = pm;
    __syncthreads();
    if (tid < 64) {
        float mm = fmaxf(fmaxf(feat[0][tid], feat[1][tid]),
                         fmaxf(feat[2][tid], feat[3][tid]));
        FMID[((size_t)gs << 6) + tid] = mm;
    }
}

// K4: q/k/v projections for attention block 2 (rows = B*2048)
__global__ __launch_bounds__(256) void k_qkv2(
    const float* __restrict__ FMID, const float* __restrict__ NXYZ,
    const float* __restrict__ wq, const float* __restrict__ wk,
    const float* __restrict__ wv, const float* __restrict__ wp,
    const float* __restrict__ bpv,
    float* __restrict__ Q2, float* __restrict__ K2, float* __restrict__ V2) {
    __shared__ float f[4][65];
    int tid = threadIdx.x;
    int lr = tid >> 6, d = tid & 63;
    size_t row = (size_t)blockIdx.x * 4 + lr;
    f[lr][d] = FMID[row * 64 + d];
    __syncthreads();
    float aq = 0.f, ak = 0.f, av = 0.f;
    for (int kk = 0; kk < 64; ++kk) {
        float fv = f[lr][kk];
        aq = fmaf(fv, wq[kk * 64 + d], aq);
        ak = fmaf(fv, wk[kk * 64 + d], ak);
        av = fmaf(fv, wv[kk * 64 + d], av);
    }
    float p0 = NXYZ[row * 3], p1 = NXYZ[row * 3 + 1], p2 = NXYZ[row * 3 + 2];
    av += fmaf(p2, wp[128 + d], fmaf(p1, wp[64 + d], p0 * wp[d])) + bpv[d];
    Q2[row * 64 + d] = aq; K2[row * 64 + d] = ak; V2[row * 64 + d] = av;
}

// K5: attention block 2, flash-style online softmax. 16 Q-rows per block
// (4 waves x 4 rows), K/V staged in padded LDS tiles of 64 rows.
__global__ __launch_bounds__(256) void k_attn2(
    const float* __restrict__ Q2, const float* __restrict__ K2,
    const float* __restrict__ V2, const float* __restrict__ FMID,
    const float* __restrict__ wo, float* __restrict__ out1) {
    __shared__ float kT[64][65], vT[64][65], qSh[16][65];
    int tid = threadIdx.x;
    int wv = tid >> 6, lane = tid & 63;
    int b = blockIdx.x >> 7, rb = blockIdx.x & 127;
    size_t rbase = (size_t)b * SS + rb * 16;
    for (int e = tid; e < 16 * 64; e += 256) {
        int r = e >> 6, dd = e & 63;
        qSh[r][dd] = Q2[(rbase + r) * 64 + dd];
    }
    float acc[4] = {0.f, 0.f, 0.f, 0.f};
    float mr[4] = {-INFINITY, -INFINITY, -INFINITY, -INFINITY};
    float lr[4] = {0.f, 0.f, 0.f, 0.f};
    for (int tt = 0; tt < 32; ++tt) {
        __syncthreads();
        for (int e = tid; e < 4096; e += 256) {
            int r = e >> 6, dd = e & 63;
            size_t src = ((size_t)b * SS + tt * 64 + r) * 64 + dd;
            kT[r][dd] = K2[src];
            vT[r][dd] = V2[src];
        }
        __syncthreads();
#pragma unroll
        for (int rr = 0; rr < 4; ++rr) {
            int lrow = wv * 4 + rr;
            float sj = 0.f;
            for (int dd = 0; dd < 64; ++dd) sj = fmaf(qSh[lrow][dd], kT[lane][dd], sj);
            sj *= 0.125f;
            float tm = sj;
#pragma unroll
            for (int off = 32; off > 0; off >>= 1)
                tm = fmaxf(tm, __shfl_down(tm, (unsigned)off, 64));
            tm = __shfl(tm, 0, 64);
            float mnew = fmaxf(mr[rr], tm);
            float alpha = expf(mr[rr] - mnew);
            float pj = expf(sj - mnew);
            float ps = pj;
#pragma unroll
            for (int off = 32; off > 0; off >>= 1) ps += __shfl_down(ps, (unsigned)off, 64);
            ps = __shfl(ps, 0, 64);
            lr[rr] = lr[rr] * alpha + ps;
            float a2 = acc[rr] * alpha;
            for (int j = 0; j < 64; ++j) {
                float pb2 = __shfl(pj, j, 64);
                a2 = fmaf(pb2, vT[j][lane], a2);
            }
            acc[rr] = a2;
            mr[rr] = mnew;
        }
    }
#pragma unroll
    for (int rr = 0; rr < 4; ++rr) {
        int lrow = wv * 4 + rr;
        size_t row = rbase + lrow;
        float avl = acc[rr] / lr[rr];
        float o = FMID[row * 64 + lane];
        for (int kk = 0; kk < 64; ++kk) {
            float avk = __shfl(avl, kk, 64);
            o = fmaf(avk, wo[kk * 64 + lane], o);
        }
        out1[((size_t)b * 64 + lane) * SS + (size_t)(rb * 16 + lrow)] = o;
    }
}

// K6: new_xyz (B,S,3) f32 -> out0 (B,3,S) f32
__global__ void k_out0(const float* __restrict__ NXYZ, float* __restrict__ out0) {
    int e = blockIdx.x * 256 + threadIdx.x;
    if (e >= BB * 3 * SS) return;
    int s = e % SS;
    int bc = e / SS;
    int c = bc % 3;
    int b = bc / 3;
    out0[e] = NXYZ[((size_t)b * SS + s) * 3 + c];
}

extern "C" void kernel_launch(void* const* d_in, const int* in_sizes, int n_in,
                              void* d_out, int out_size, void* d_ws, size_t ws_size,
                              hipStream_t stream) {
    const float* xyz = (const float*)d_in[0];
    const float* pts = (const float*)d_in[1];
    const float* w1q = (const float*)d_in[2];
    const float* w1k = (const float*)d_in[3];
    const float* w1v = (const float*)d_in[4];
    const float* w1o = (const float*)d_in[5];
    const float* w1p = (const float*)d_in[6];
    const float* b1p = (const float*)d_in[7];
    const float* w2q = (const float*)d_in[8];
    const float* w2k = (const float*)d_in[9];
    const float* w2v = (const float*)d_in[10];
    const float* w2o = (const float*)d_in[11];
    const float* w2p = (const float*)d_in[12];
    const float* b2p = (const float*)d_in[13];

    float* X = (float*)d_ws;                               // B*N*3
    float* NXYZ = X + (size_t)BB * NN * 3;                 // B*S*3
    int* GI = (int*)(NXYZ + (size_t)BB * SS * 3);          // B*S*32
    float* FMID = (float*)(GI + (size_t)BB * SS * 32);     // B*S*64
    float* Q2 = FMID + (size_t)BB * SS * 64;
    float* K2 = Q2 + (size_t)BB * SS * 64;
    float* V2 = K2 + (size_t)BB * SS * 64;

    float* out0 = (float*)d_out;
    float* out1 = out0 + (size_t)BB * 3 * SS;

    k_transpose<<<768, 256, 0, stream>>>(xyz, X);
    k_fps<<<BB, 512, 0, stream>>>(X, NXYZ);
    k_ballq<<<4096, 256, 0, stream>>>(X, NXYZ, GI);
    k_attn1<<<16384, 256, 0, stream>>>(X, NXYZ, GI, pts, w1q, w1k, w1v, w1o,
                                       w1p, b1p, FMID);
    k_qkv2<<<4096, 256, 0, stream>>>(FMID, NXYZ, w2q, w2k, w2v, w2p, b2p,
                                     Q2, K2, V2);
    k_attn2<<<1024, 256, 0, stream>>>(Q2, K2, V2, FMID, w2o, out1);
    k_out0<<<192, 256, 0, stream>>>(NXYZ, out0);
}

// Round 7
// 3665.638 us; speedup vs baseline: 1.8037x; 1.3869x over previous
//
#include <hip/hip_runtime.h>
#include <hip/hip_bf16.h>
#include <math.h>

#define BB 8
#define NN 8192
#define SS 2048
#define NSAMP 32

typedef unsigned long long u64;

// K0: transpose xyz (B,3,N) f32 -> X (B,N,3) f32
__global__ void k_transpose(const float* __restrict__ xyz, float* __restrict__ X) {
    int e = blockIdx.x * 256 + threadIdx.x;
    if (e >= BB * 3 * NN) return;
    int n = e % NN;
    int bc = e / NN;
    int c = bc % 3;
    int b = bc / 3;
    X[((size_t)(b * NN + n)) * 3 + c] = xyz[e];
}

// K1: farthest point sampling, one block per batch.
// ARITHMETIC FROZEN (bit-exact vs reference, r18 PASS): direct distance,
// ascending, separately rounded (NO FMA); dists=fminf; argmax=first-max
// (smallest global index on ties; (v,n) lexicographic max is associative &
// commutative so combine order across chains/waves/tree is free).
// History: r19 remat 3.0ms; r22 LDS-pts 3.9ms (DS latency); r24 1024thr
// 4.9ms (DS throughput + bigger tail); r25 reg-resident @512thr (VGPR 88
// confirms) 3.4ms — still ~4020 cyc/step vs ~1700 model.
// r26 root cause of the systematic ~2K cyc/step residual in ALL versions:
//  (1) tid0's 3x global_store of NXYZ before __syncthreads: compiler emits
//      s_waitcnt vmcnt(0) before s_barrier -> wave 0 eats HBM/L2 write-ack
//      (~300-900 cyc) EVERY step and 7 waves wait behind it.
//      FIX: buffer outputs in 24 KB LDS (nbuf), dump once after the loop.
//  (2) __shfl_down = ds_bpermute: 6 DEPENDENT DS-pipe stages (~400-700 cyc
//      latency chain) + 16-load cross-wave scan.
//      FIX: pack (v,n) as u64 key = (bits(v)<<32)|~n  [valid: bestv>=+0
//      always after in-thread combine (sums of squares, no -0/NaN), IEEE
//      bits order-isomorphic for non-negatives; u64 max == value-max with
//      smallest-n tie-break, EXACT frozen semantics]. Reduce with 6 DPP
//      stages on the VALU pipe (row_ror 1/2/4/8 + bcast15 + bcast31,
//      ~100 cyc total), lane 63 holds the wave max. Cross-wave = 8 u64
//      LDS entries, same lexicographic scan.
// Budget: dist 830 + dpp 100 + barrier ~150 + scan ~220 + bcast ~130
// ~= 1500-2000 cyc/step.
__device__ __forceinline__ u64 fps_wave_max(u64 key) {
    // 6-stage full-wave max on packed keys. update_dpp(old=own, src=own):
    // lanes not written by the pattern keep their own value (no-op in max);
    // even if bound_ctrl zeroes them, 0 never wins (keys > 0). Safe either way.
#define FPS_DPP_STAGE(CTRL)                                                   \
    {                                                                         \
        int lo = (int)(unsigned)(key & 0xffffffffull);                        \
        int hi = (int)(unsigned)(key >> 32);                                  \
        int lo2 = __builtin_amdgcn_update_dpp(lo, lo, CTRL, 0xF, 0xF, false); \
        int hi2 = __builtin_amdgcn_update_dpp(hi, hi, CTRL, 0xF, 0xF, false); \
        u64 k2 = ((u64)(unsigned)hi2 << 32) | (unsigned)lo2;                  \
        if (k2 > key) key = k2;                                               \
    }
    FPS_DPP_STAGE(0x121)  // row_ror:1
    FPS_DPP_STAGE(0x122)  // row_ror:2
    FPS_DPP_STAGE(0x124)  // row_ror:4
    FPS_DPP_STAGE(0x128)  // row_ror:8  -> all lanes hold their row(16) max
    FPS_DPP_STAGE(0x142)  // row_bcast15: rows 1,3 absorb rows 0,2
    FPS_DPP_STAGE(0x143)  // row_bcast31: upper half absorbs lower
#undef FPS_DPP_STAGE
    return key;  // lanes 48..63 (esp. 63) hold the full wave max
}

__global__ __launch_bounds__(512)
__attribute__((amdgpu_waves_per_eu(2, 2))) void k_fps(
    const float* __restrict__ X, float* __restrict__ NXYZ) {
    __shared__ float lx[NN], ly[NN], lz[NN];  // 96 KB winner-broadcast cache
    __shared__ float nbuf[SS * 3];            // 24 KB result buffer
    __shared__ u64 wk_[2][8];
    int b = blockIdx.x;
    int tid = threadIdx.x;
    const float* xb = X + (size_t)b * NN * 3;
    float px[16], py[16], pz[16], dist[16];
#pragma unroll
    for (int i = 0; i < 16; ++i) {
        int n = tid + (i << 9);
        px[i] = xb[(size_t)n * 3 + 0];
        py[i] = xb[(size_t)n * 3 + 1];
        pz[i] = xb[(size_t)n * 3 + 2];
        dist[i] = 1e10f;
        lx[n] = px[i]; ly[n] = py[i]; lz[n] = pz[i];  // stage broadcast mirror
    }
    // Opaque defs: keep the loaded values as register definitions (r25: works,
    // VGPR 88 => resident; remat of an asm output is illegal).
#pragma unroll
    for (int i = 0; i < 16; ++i) {
        asm volatile("" : "+v"(px[i]), "+v"(py[i]), "+v"(pz[i]));
    }
    float c0 = xb[0], c1 = xb[1], c2 = xb[2];
    int lane = tid & 63, wv = tid >> 6;  // wv in 0..7
    __syncthreads();
    for (int t = 0; t < SS; ++t) {
        if (tid == 0) {  // LDS-only; no global store in the loop
            nbuf[t * 3 + 0] = c0; nbuf[t * 3 + 1] = c1; nbuf[t * 3 + 2] = c2;
        }
        // 4 independent scan chains over ascending i-blocks; strict > keeps
        // the first (smallest-n) max within a chain; chains combined in
        // ascending-n order with strict > => identical to sequential
        // first-max over i=0..15.
        float bv0 = -1.0f, bv1 = -1.0f, bv2 = -1.0f, bv3 = -1.0f;
        int bn0 = 0, bn1 = 0, bn2 = 0, bn3 = 0;
#pragma unroll
        for (int i = 0; i < 16; ++i) {
            float dx = __fsub_rn(px[i], c0);
            float dy = __fsub_rn(py[i], c1);
            float dz = __fsub_rn(pz[i], c2);
            float dd = __fadd_rn(__fadd_rn(__fmul_rn(dx, dx), __fmul_rn(dy, dy)),
                                 __fmul_rn(dz, dz));
            float nd = fminf(dist[i], dd);
            dist[i] = nd;
            int n = tid + (i << 9);
            if (i < 4) {
                if (nd > bv0) { bv0 = nd; bn0 = n; }
            } else if (i < 8) {
                if (nd > bv1) { bv1 = nd; bn1 = n; }
            } else if (i < 12) {
                if (nd > bv2) { bv2 = nd; bn2 = n; }
            } else {
                if (nd > bv3) { bv3 = nd; bn3 = n; }
            }
        }
        float bestv = bv0; int bestn = bn0;
        if (bv1 > bestv) { bestv = bv1; bestn = bn1; }
        if (bv2 > bestv) { bestv = bv2; bestn = bn2; }
        if (bv3 > bestv) { bestv = bv3; bestn = bn3; }
        // bestv >= +0 here (>= one nd >= 0 replaced the -1 sentinel), so the
        // packed key ordering is exactly (value, smallest-index) lexicographic.
        u64 key = ((u64)__float_as_uint(bestv) << 32) | (unsigned)(~bestn);
        key = fps_wave_max(key);
        int pbuf = t & 1;
        if (lane == 63) wk_[pbuf][wv] = key;
        __syncthreads();
        // 8-entry cross-wave scan on packed keys (u64 max, same semantics)
        u64 kmax = wk_[pbuf][0];
#pragma unroll
        for (int i = 1; i < 8; ++i) {
            u64 k = wk_[pbuf][i];
            if (k > kmax) kmax = k;
        }
        int kn = (int)(~(unsigned)(kmax & 0xffffffffull));
        // broadcast LDS read of the winner's coords (bit-identical copy)
        c0 = lx[kn]; c1 = ly[kn]; c2 = lz[kn];
        // no trailing barrier: next step writes the other wk_ slot; the
        // write-after-next is separated from this read by the next barrier.
    }
    __syncthreads();
    // single coalesced dump of the 24 KB result buffer
    float* ob = NXYZ + (size_t)b * SS * 3;
    for (int e = tid; e < SS * 3; e += 512) ob[e] = nbuf[e];
}

// K2: ball query. One wave per center. ARITHMETIC FROZEN (r18 PASS):
//   dot = fma(c2,x2, fma(c1,x1, fl(c0*x0)))   (BLAS k=3 asc-FMA)
//   t   = fl(-2*dot + B)   B = (x0^2+x1^2)+x2^2  (asc, no FMA)
//   sqr = fl(t + A)        A = (c0^2+c1^2)+c2^2  (asc, no FMA)
//   exclude sqr > 0.04f
__global__ __launch_bounds__(256) void k_ballq(const float* __restrict__ X,
                                               const float* __restrict__ NXYZ,
                                               int* __restrict__ GI) {
    int wv = threadIdx.x >> 6, lane = threadIdx.x & 63;
    int gs = blockIdx.x * 4 + wv;           // 0..16383
    int b = gs >> 11;
    const float* xb = X + (size_t)b * NN * 3;
    float c0 = NXYZ[(size_t)gs * 3 + 0];
    float c1 = NXYZ[(size_t)gs * 3 + 1];
    float c2 = NXYZ[(size_t)gs * 3 + 2];
    float A = __fadd_rn(__fadd_rn(__fmul_rn(c0, c0), __fmul_rn(c1, c1)),
                        __fmul_rn(c2, c2));
    const float R2 = 0.04f;
    int cnt = 0, first = 0;
    int* gout = GI + ((size_t)gs << 5);
    for (int r = 0; r < 128 && cnt < 32; ++r) {
        int n = (r << 6) + lane;
        float x0 = xb[(size_t)n * 3 + 0];
        float x1 = xb[(size_t)n * 3 + 1];
        float x2 = xb[(size_t)n * 3 + 2];
        float Bx = __fadd_rn(__fadd_rn(__fmul_rn(x0, x0), __fmul_rn(x1, x1)),
                             __fmul_rn(x2, x2));
        float dot = fmaf(c2, x2, fmaf(c1, x1, __fmul_rn(c0, x0)));  // BLAS asc-FMA
        float t = __fadd_rn(__fmul_rn(-2.0f, dot), Bx);             // += B first
        float sqr = __fadd_rn(t, A);                                // += A second
        bool pred = !(sqr > R2);
        u64 mask = __ballot(pred);
        int rank = cnt + __popcll(mask & ((1ull << lane) - 1ull));
        if (pred && rank < 32) gout[rank] = n;
        if (cnt == 0 && mask) first = (r << 6) + (__ffsll((long long)mask) - 1);
        cnt += __popcll(mask);
    }
    if (cnt < 32 && lane >= cnt && lane < 32) gout[lane] = first;
}

// K3: build group features in LDS + attention block 1 + maxpool. One block per
// (b,s) group: 32 tokens x 64 dims.
__global__ __launch_bounds__(256) void k_attn1(
    const float* __restrict__ X, const float* __restrict__ NXYZ,
    const int* __restrict__ GI, const float* __restrict__ P,
    const float* __restrict__ wq, const float* __restrict__ wk,
    const float* __restrict__ wv, const float* __restrict__ wo,
    const float* __restrict__ wp, const float* __restrict__ bp,
    float* __restrict__ FMID) {
    __shared__ float feat[32][65], qS[32][65], kS[32][65], vS[32][65];
    __shared__ float sc[32][33];
    __shared__ float pos[32][3];
    __shared__ int giS[32];
    __shared__ float ctr[3];
    int gs = blockIdx.x;
    int b = gs >> 11;
    int tid = threadIdx.x;
    if (tid < 32) giS[tid] = GI[((size_t)gs << 5) + tid];
    if (tid < 3) ctr[tid] = NXYZ[(size_t)gs * 3 + tid];
    __syncthreads();
    const float* xb = X + (size_t)b * NN * 3;
    const float* pb = P + (size_t)b * 61 * NN;
    int d = tid & 63, g4 = tid >> 6;
    for (int jj = 0; jj < 8; ++jj) {
        int j = g4 * 8 + jj;
        int idx = giS[j];
        float val;
        if (d < 3) {
            float xv = xb[(size_t)idx * 3 + d];
            pos[j][d] = xv;
            val = __fsub_rn(xv, ctr[d]);
        } else {
            val = pb[(size_t)(d - 3) * NN + idx];
        }
        feat[j][d] = val;
    }
    __syncthreads();
    float aq[8], ak[8], av[8];
#pragma unroll
    for (int i = 0; i < 8; ++i) { aq[i] = 0.f; ak[i] = 0.f; av[i] = 0.f; }
    for (int kk = 0; kk < 64; ++kk) {
        float wqv = wq[kk * 64 + d];
        float wkv = wk[kk * 64 + d];
        float wvv = wv[kk * 64 + d];
#pragma unroll
        for (int i = 0; i < 8; ++i) {
            float f = feat[g4 + 4 * i][kk];
            aq[i] = fmaf(f, wqv, aq[i]);
            ak[i] = fmaf(f, wkv, ak[i]);
            av[i] = fmaf(f, wvv, av[i]);
        }
    }
    {
        float wp0 = wp[d], wp1 = wp[64 + d], wp2 = wp[128 + d];
        float bpd = bp[d];
#pragma unroll
        for (int i = 0; i < 8; ++i) {
            int j = g4 + 4 * i;
            float pterm = fmaf(pos[j][2], wp2, fmaf(pos[j][1], wp1, pos[j][0] * wp0)) + bpd;
            av[i] += pterm;
            qS[j][d] = aq[i]; kS[j][d] = ak[i]; vS[j][d] = av[i];
        }
    }
    __syncthreads();
    for (int e = tid; e < 1024; e += 256) {
        int r = e >> 5, ci = e & 31;
        float acc = 0.f;
        for (int kk = 0; kk < 64; ++kk) acc = fmaf(qS[r][kk], kS[ci][kk], acc);
        sc[r][ci] = acc * 0.125f;
    }
    __syncthreads();
    if (tid < 32) {
        float m = -INFINITY;
        for (int i2 = 0; i2 < 32; ++i2) m = fmaxf(m, sc[tid][i2]);
        float sum = 0.f;
        for (int i2 = 0; i2 < 32; ++i2) {
            float e2 = expf(sc[tid][i2] - m);
            sc[tid][i2] = e2; sum += e2;
        }
        float inv = 1.0f / sum;
        for (int i2 = 0; i2 < 32; ++i2) sc[tid][i2] *= inv;
    }
    __syncthreads();
    // a @ v -> reuse qS as attention output
    for (int e = tid; e < 2048; e += 256) {
        int j = e >> 6, dd2 = e & 63;
        float acc = 0.f;
        for (int s2 = 0; s2 < 32; ++s2) acc = fmaf(sc[j][s2], vS[s2][dd2], acc);
        qS[j][dd2] = acc;
    }
    __syncthreads();
    float o[8];
#pragma unroll
    for (int i = 0; i < 8; ++i) o[i] = feat[g4 + 4 * i][d];
    for (int kk = 0; kk < 64; ++kk) {
        float wov = wo[kk * 64 + d];
#pragma unroll
        for (int i = 0; i < 8; ++i) o[i] = fmaf(qS[g4 + 4 * i][kk], wov, o[i]);
    }
    float pm = o[0];
#pragma unroll
    for (int i = 1; i < 8; ++i) pm = fmaxf(pm, o[i]);
    __syncthreads();
    feat[g4][d] = pm;
    __syncthreads();
    if (tid < 64) {
        float mm = fmaxf(fmaxf(feat[0][tid], feat[1][tid]),
                         fmaxf(feat[2][tid], feat[3][tid]));
        FMID[((size_t)gs << 6) + tid] = mm;
    }
}

// K4: q/k/v projections for attention block 2 (rows = B*2048)
__global__ __launch_bounds__(256) void k_qkv2(
    const float* __restrict__ FMID, const float* __restrict__ NXYZ,
    const float* __restrict__ wq, const float* __restrict__ wk,
    const float* __restrict__ wv, const float* __restrict__ wp,
    const float* __restrict__ bpv,
    float* __restrict__ Q2, float* __restrict__ K2, float* __restrict__ V2) {
    __shared__ float f[4][65];
    int tid = threadIdx.x;
    int lr = tid >> 6, d = tid & 63;
    size_t row = (size_t)blockIdx.x * 4 + lr;
    f[lr][d] = FMID[row * 64 + d];
    __syncthreads();
    float aq = 0.f, ak = 0.f, av = 0.f;
    for (int kk = 0; kk < 64; ++kk) {
        float fv = f[lr][kk];
        aq = fmaf(fv, wq[kk * 64 + d], aq);
        ak = fmaf(fv, wk[kk * 64 + d], ak);
        av = fmaf(fv, wv[kk * 64 + d], av);
    }
    float p0 = NXYZ[row * 3], p1 = NXYZ[row * 3 + 1], p2 = NXYZ[row * 3 + 2];
    av += fmaf(p2, wp[128 + d], fmaf(p1, wp[64 + d], p0 * wp[d])) + bpv[d];
    Q2[row * 64 + d] = aq; K2[row * 64 + d] = ak; V2[row * 64 + d] = av;
}

// K5: attention block 2, flash-style online softmax. 16 Q-rows per block
// (4 waves x 4 rows), K/V staged in padded LDS tiles of 64 rows.
__global__ __launch_bounds__(256) void k_attn2(
    const float* __restrict__ Q2, const float* __restrict__ K2,
    const float* __restrict__ V2, const float* __restrict__ FMID,
    const float* __restrict__ wo, float* __restrict__ out1) {
    __shared__ float kT[64][65], vT[64][65], qSh[16][65];
    int tid = threadIdx.x;
    int wv = tid >> 6, lane = tid & 63;
    int b = blockIdx.x >> 7, rb = blockIdx.x & 127;
    size_t rbase = (size_t)b * SS + rb * 16;
    for (int e = tid; e < 16 * 64; e += 256) {
        int r = e >> 6, dd = e & 63;
        qSh[r][dd] = Q2[(rbase + r) * 64 + dd];
    }
    float acc[4] = {0.f, 0.f, 0.f, 0.f};
    float mr[4] = {-INFINITY, -INFINITY, -INFINITY, -INFINITY};
    float lr[4] = {0.f, 0.f, 0.f, 0.f};
    for (int tt = 0; tt < 32; ++tt) {
        __syncthreads();
        for (int e = tid; e < 4096; e += 256) {
            int r = e >> 6, dd = e & 63;
            size_t src = ((size_t)b * SS + tt * 64 + r) * 64 + dd;
            kT[r][dd] = K2[src];
            vT[r][dd] = V2[src];
        }
        __syncthreads();
#pragma unroll
        for (int rr = 0; rr < 4; ++rr) {
            int lrow = wv * 4 + rr;
            float sj = 0.f;
            for (int dd = 0; dd < 64; ++dd) sj = fmaf(qSh[lrow][dd], kT[lane][dd], sj);
            sj *= 0.125f;
            float tm = sj;
#pragma unroll
            for (int off = 32; off > 0; off >>= 1)
                tm = fmaxf(tm, __shfl_down(tm, (unsigned)off, 64));
            tm = __shfl(tm, 0, 64);
            float mnew = fmaxf(mr[rr], tm);
            float alpha = expf(mr[rr] - mnew);
            float pj = expf(sj - mnew);
            float ps = pj;
#pragma unroll
            for (int off = 32; off > 0; off >>= 1) ps += __shfl_down(ps, (unsigned)off, 64);
            ps = __shfl(ps, 0, 64);
            lr[rr] = lr[rr] * alpha + ps;
            float a2 = acc[rr] * alpha;
            for (int j = 0; j < 64; ++j) {
                float pb2 = __shfl(pj, j, 64);
                a2 = fmaf(pb2, vT[j][lane], a2);
            }
            acc[rr] = a2;
            mr[rr] = mnew;
        }
    }
#pragma unroll
    for (int rr = 0; rr < 4; ++rr) {
        int lrow = wv * 4 + rr;
        size_t row = rbase + lrow;
        float avl = acc[rr] / lr[rr];
        float o = FMID[row * 64 + lane];
        for (int kk = 0; kk < 64; ++kk) {
            float avk = __shfl(avl, kk, 64);
            o = fmaf(avk, wo[kk * 64 + lane], o);
        }
        out1[((size_t)b * 64 + lane) * SS + (size_t)(rb * 16 + lrow)] = o;
    }
}

// K6: new_xyz (B,S,3) f32 -> out0 (B,3,S) f32
__global__ void k_out0(const float* __restrict__ NXYZ, float* __restrict__ out0) {
    int e = blockIdx.x * 256 + threadIdx.x;
    if (e >= BB * 3 * SS) return;
    int s = e % SS;
    int bc = e / SS;
    int c = bc % 3;
    int b = bc / 3;
    out0[e] = NXYZ[((size_t)b * SS + s) * 3 + c];
}

extern "C" void kernel_launch(void* const* d_in, const int* in_sizes, int n_in,
                              void* d_out, int out_size, void* d_ws, size_t ws_size,
                              hipStream_t stream) {
    const float* xyz = (const float*)d_in[0];
    const float* pts = (const float*)d_in[1];
    const float* w1q = (const float*)d_in[2];
    const float* w1k = (const float*)d_in[3];
    const float* w1v = (const float*)d_in[4];
    const float* w1o = (const float*)d_in[5];
    const float* w1p = (const float*)d_in[6];
    const float* b1p = (const float*)d_in[7];
    const float* w2q = (const float*)d_in[8];
    const float* w2k = (const float*)d_in[9];
    const float* w2v = (const float*)d_in[10];
    const float* w2o = (const float*)d_in[11];
    const float* w2p = (const float*)d_in[12];
    const float* b2p = (const float*)d_in[13];

    float* X = (float*)d_ws;                               // B*N*3
    float* NXYZ = X + (size_t)BB * NN * 3;                 // B*S*3
    int* GI = (int*)(NXYZ + (size_t)BB * SS * 3);          // B*S*32
    float* FMID = (float*)(GI + (size_t)BB * SS * 32);     // B*S*64
    float* Q2 = FMID + (size_t)BB * SS * 64;
    float* K2 = Q2 + (size_t)BB * SS * 64;
    float* V2 = K2 + (size_t)BB * SS * 64;

    float* out0 = (float*)d_out;
    float* out1 = out0 + (size_t)BB * 3 * SS;

    k_transpose<<<768, 256, 0, stream>>>(xyz, X);
    k_fps<<<BB, 512, 0, stream>>>(X, NXYZ);
    k_ballq<<<4096, 256, 0, stream>>>(X, NXYZ, GI);
    k_attn1<<<16384, 256, 0, stream>>>(X, NXYZ, GI, pts, w1q, w1k, w1v, w1o,
                                       w1p, b1p, FMID);
    k_qkv2<<<4096, 256, 0, stream>>>(FMID, NXYZ, w2q, w2k, w2v, w2p, b2p,
                                     Q2, K2, V2);
    k_attn2<<<1024, 256, 0, stream>>>(Q2, K2, V2, FMID, w2o, out1);
    k_out0<<<192, 256, 0, stream>>>(NXYZ, out0);
}